// Round 3
// baseline (174.272 us; speedup 1.0000x reference)
//
#include <hip/hip_runtime.h>
#include <hip/hip_bf16.h>
#include <stdint.h>

// Problem constants (fixed by reference)
#define T_TASKS 8
#define DM      1024
#define HID     1024
#define NC      100
#define NCP     128
#define BATCH   8192
#define MPAD    9216      // 8192 + 8*128 worst-case 128-aligned padding

typedef __bf16 bf16x8 __attribute__((ext_vector_type(8)));
typedef float  f32x4  __attribute__((ext_vector_type(4)));
typedef unsigned int u32;
#define GAS __attribute__((address_space(1)))
#define LAS __attribute__((address_space(3)))

__device__ __forceinline__ unsigned short f2bf(float f) {
  __hip_bfloat16 h = __float2bfloat16(f);
  return __builtin_bit_cast(unsigned short, h);
}

__device__ __forceinline__ float bf2f(unsigned short u) {
  const u32 v = ((u32)u) << 16;
  return __builtin_bit_cast(float, v);
}

// ---------------------------------------------------------------------------
// sortpre_k: one launch, four roles (round-3: adds Out=b2 init role; reduce_k
// is gone — gemm accumulates into Out with f32 atomics).
//  [0, 32)       : sort -> perm/starts (each block redundantly computes
//                  totals+prefix from all 8192 task_ids; fills pads analytically)
//  [32, 2080)    : W1 [t][d][h] fp32 -> W1T [t][h][d] bf16 (vectorized)
//  [2080, 2208)  : W2 -> W2F fragment-packed bf16 (verified r5-r8)
//  [2208, 3232)  : Out[r][c] = b2[task_id[r]][c]  (8 rows/block, scalar —
//                  100-float rows are not 16B-aligned for odd rows)
// ---------------------------------------------------------------------------
#define SORT_BLKS 32
#define W1_BLKS (T_TASKS * 16 * 16)
#define W2_BLKS (16 * T_TASKS)
#define OUT_BLKS (BATCH / 8)
__global__ void sortpre_k(const int* __restrict__ task_id,
                          const float* __restrict__ W1,
                          unsigned short* __restrict__ W1T,
                          const float* __restrict__ W2,
                          unsigned short* __restrict__ W2F,
                          const float* __restrict__ b2,
                          float* __restrict__ Out,
                          int* __restrict__ perm, int* __restrict__ starts) {
  __shared__ __align__(16) unsigned short tile[128 * 72];   // 18,432 B
  __shared__ int sAux[25];                                  // tot[8] prev[8] sst[9]
  const int bid = blockIdx.x;
  const int tid = threadIdx.x;

  if (bid < SORT_BLKS) {
    // ---- sort role ----
    int* hist = (int*)tile;            // [256][8] per-chunk histograms (8 KB)
    int* tot  = sAux;
    int* prev = sAux + 8;
    int* sst  = sAux + 16;             // 9 entries
#pragma unroll
    for (int t = 0; t < T_TASKS; ++t) hist[tid * 8 + t] = 0;
    __syncthreads();
    // chunk tid covers ids [tid*32, tid*32+32)
    const int cbase = tid * 32;
    for (int i = 0; i < 32; ++i) {
      const int t = task_id[cbase + i];
      hist[tid * 8 + t] += 1;
    }
    __syncthreads();
    if (tid < T_TASKS) {               // totals over all 256 chunks
      int s = 0;
      for (int r = 0; r < 256; ++r) s += hist[r * 8 + tid];
      tot[tid] = s;
    } else if (tid < 2 * T_TASKS) {    // prefix: chunks before this stripe
      const int t = tid - T_TASKS;
      const int lim = bid * 8;         // stripe [bid*256, ...) = chunks [bid*8, ...)
      int s = 0;
      for (int r = 0; r < lim; ++r) s += hist[r * 8 + t];
      prev[t] = s;
    }
    __syncthreads();
    if (tid == 0) {
      int off = 0;
      for (int t = 0; t < T_TASKS; ++t) { sst[t] = off; off += (tot[t] + 127) & ~127; }
      sst[T_TASKS] = off;
    }
    if (tid < T_TASKS) hist[tid] = 0;  // reuse as stripe slot counters
    __syncthreads();
    // scatter my 256 rows
    const int r = bid * 256 + tid;
    const int t = task_id[r];
    const int slot = atomicAdd(&hist[t], 1);
    perm[sst[t] + prev[t] + slot] = r;
    // pads: exactly MPAD-BATCH = 1024 positions never scattered-to
    // (per-task alignment gaps + the tail [sst[8], MPAD)). 32 per block.
    if (tid < 32) {
      const int g = bid * 32 + tid;
      int acc = 0, pos = -1;
#pragma unroll
      for (int t2 = 0; t2 < T_TASKS; ++t2) {
        const int pc = sst[t2 + 1] - sst[t2] - tot[t2];
        if (pos < 0 && g < acc + pc) pos = sst[t2] + tot[t2] + (g - acc);
        acc += pc;
      }
      if (pos < 0) pos = sst[T_TASKS] + (g - acc);   // tail segment
      perm[pos] = -1;
    }
    if (bid == 0 && tid <= T_TASKS) starts[tid] = sst[tid];
    return;
  }

  if (bid < SORT_BLKS + W1_BLKS) {
    // ---- W1 transpose, vectorized global sides ----
    const int b  = bid - SORT_BLKS;
    const int t  = b >> 8;
    const int rem = b & 255;
    const int d0 = (rem >> 4) * 64;
    const int h0 = (rem & 15) * 64;
    const float* src = W1 + (size_t)t * DM * HID;
    unsigned short* dst = W1T + (size_t)t * HID * DM;
    // phase 1: float4 loads over h; scalar u16 LDS stores into tile[h][d]
#pragma unroll
    for (int i = 0; i < 4; ++i) {
      const int idx = tid + 256 * i;           // 1024 float4 = 64d x 16 chunks
      const int d  = idx >> 4;
      const int hc = (idx & 15) * 4;
      const float4 f = *(const float4*)(src + (size_t)(d0 + d) * HID + h0 + hc);
      tile[(hc + 0) * 65 + d] = f2bf(f.x);
      tile[(hc + 1) * 65 + d] = f2bf(f.y);
      tile[(hc + 2) * 65 + d] = f2bf(f.z);
      tile[(hc + 3) * 65 + d] = f2bf(f.w);
    }
    __syncthreads();
    // phase 2: scalar u16 LDS reads; ushort8 (16B) global stores
#pragma unroll
    for (int i = 0; i < 2; ++i) {
      const int idx = tid + 256 * i;           // 512 ushort8 = 64h x 8 chunks
      const int lh  = idx >> 3;
      const int ldc = idx & 7;
      union { uint4 v; unsigned short s[8]; } o;
#pragma unroll
      for (int q = 0; q < 8; ++q) o.s[q] = tile[lh * 65 + ldc * 8 + q];
      *(uint4*)(dst + (size_t)(h0 + lh) * DM + d0 + ldc * 8) = o.v;
    }
    return;
  }

  if (bid < SORT_BLKS + W1_BLKS + W2_BLKS) {
    // ---- W2 -> frag-packed W2F ----
    const int b  = bid - (SORT_BLKS + W1_BLKS);
    const int t  = b >> 4;
    const int h0 = (b & 15) * 64;
    const float* src = W2 + (size_t)t * HID * NC;
#pragma unroll
    for (int i = 0; i < 36; ++i) tile[tid + 256 * i] = 0;
    __syncthreads();
#pragma unroll
    for (int i = 0; i < 32; ++i) {
      const int idx = tid + 256 * i;
      const int row = idx >> 7, col = idx & 127;
      if (col < NC)
        tile[col * 72 + row] = f2bf(src[(size_t)(h0 + row) * NC + col]);
    }
    __syncthreads();
    const int w = tid >> 6, lane = tid & 63;
    const int lr = lane & 15, quad = lane >> 4;
#pragma unroll
    for (int e = 0; e < 4; ++e) {
      const int fi = w * 4 + e;
      const int ci = fi >> 1, kcl = fi & 1;
      const uint4 v = *(const uint4*)&tile[(ci * 16 + lr) * 72 + kcl * 32 + quad * 8];
      unsigned short* dstp =
          W2F + (((size_t)t * 8 + ci) * 32 + (h0 >> 5) + kcl) * 512 + lane * 8;
      *(uint4*)dstp = v;
    }
    return;
  }

  // ---- Out = b2[task] init (gemm atomically accumulates on top) ----
  {
    const int b = bid - (SORT_BLKS + W1_BLKS + W2_BLKS);
    const int row = b * 8 + (tid >> 5);
    const int c = (tid & 31) * 4;
    if (c < NC) {
      const int t = task_id[row];
      const float* src = b2 + (size_t)t * NC + c;
      float* dst = Out + (size_t)row * NC + c;
      dst[0] = src[0]; dst[1] = src[1]; dst[2] = src[2]; dst[3] = src[3];
    }
  }
}

// ---------------------------------------------------------------------------
// gather_k: gather+convert x rows -> permuted bf16 XP (pads=0). grid MPAD.
// ---------------------------------------------------------------------------
__global__ void gather_k(const float* __restrict__ x,
                         const int* __restrict__ perm,
                         unsigned short* __restrict__ XP) {
  const int bid = blockIdx.x;
  const int tid = threadIdx.x;
  const int r = perm[bid];
  const int c = tid * 4;
  ushort4 v;
  if (r >= 0) {
    const float4 f = *(const float4*)(x + (size_t)r * DM + c);
    v.x = f2bf(f.x); v.y = f2bf(f.y); v.z = f2bf(f.z); v.w = f2bf(f.w);
  } else {
    v.x = 0; v.y = 0; v.z = 0; v.w = 0;
  }
  *(ushort4*)(XP + (size_t)bid * DM + c) = v;
}

// ---------------------------------------------------------------------------
// Fused MLP GEMM — round-3 change: epilogue writes f32 atomics straight into
// Out (b2 pre-added by sortpre role); Lp and reduce_k deleted. perm rows for
// this tile cached in LDS (ogS). K-loop / MFMA core unchanged (proven).
// XCD supertile swizzle kept: all 8 by-blocks of one bx land on one XCD, so
// the 8-way atomic contention per Out address resolves in a single L2.
// ---------------------------------------------------------------------------
__global__ __launch_bounds__(256, 3) void gemm_fused4(
    const unsigned short* __restrict__ XP,     // [MPAD][1024] bf16 permuted
    const unsigned short* __restrict__ W1T,    // [T][HID][1024] bf16
    const unsigned short* __restrict__ W2F,    // [T][8][32][512] frag-packed
    const float* __restrict__ b1,              // [T][HID]
    const int* __restrict__ starts,            // [9]
    const int* __restrict__ perm,              // [MPAD]
    float* __restrict__ Out)                   // [BATCH][NC] f32
{
  __shared__ __align__(16) unsigned short lds[18432];  // 36,864 B
  __shared__ int ogS[128];
  unsigned short* As = lds;
  unsigned short* Bs = lds + 8192;
  unsigned short* hS = lds;                    // reuse: [128][136]

  const int tid = threadIdx.x;

  // XCD supertile swizzle: dispatch-linear L -> (bx, by) so that each XCD
  // gets a contiguous 9-wide bx chunk across all 8 by values.
  const int L   = blockIdx.y * gridDim.x + blockIdx.x;  // x-fastest dispatch
  const int xcd = L & 7;
  const int idx = L >> 3;                                // 0..71
  const int bx  = xcd * 9 + (idx % 9);
  const int by  = idx / 9;

  const int p0  = bx * 128;
  const int n0  = by * 128;

  if (p0 >= starts[T_TASKS]) return;

  if (tid < 128) ogS[tid] = perm[p0 + tid];

  int task = 0;
#pragma unroll
  for (int t = 1; t < T_TASKS; ++t)
    if (p0 >= starts[t]) task = t;

  const int wave = tid >> 6;
  const int lane = tid & 63;
  const int wm   = (wave >> 1) * 64;
  const int wn   = (wave & 1) * 64;
  const int lr   = lane & 15;
  const int quad = lane >> 4;

  const int crow = tid >> 3;
  const int kc   = (tid & 7) ^ (crow & 7);
  const unsigned short* pA[4];
  const unsigned short* pB[4];
  const unsigned short* Bg = W1T + ((size_t)task * HID + n0) * 1024;
#pragma unroll
  for (int i = 0; i < 4; ++i) {
    const int row = crow + 32 * i;
    pA[i] = XP + (size_t)(p0 + row) * 1024 + kc * 8;
    pB[i] = Bg + (size_t)row * 1024 + kc * 8;
  }

  f32x4 acc[4][4];
#pragma unroll
  for (int i = 0; i < 4; ++i)
#pragma unroll
    for (int j = 0; j < 4; ++j) acc[i][j] = (f32x4){0.f, 0.f, 0.f, 0.f};

  const int sw0 = quad ^ (lr & 7);
  const int sw1 = (4 + quad) ^ (lr & 7);

  for (int k0 = 0; k0 < 1024; k0 += 64) {
#pragma unroll
    for (int i = 0; i < 4; ++i) {
      __builtin_amdgcn_global_load_lds((const GAS u32*)(pA[i] + k0),
                                       (LAS u32*)&As[(tid + 256 * i) * 8], 16, 0, 0);
      __builtin_amdgcn_global_load_lds((const GAS u32*)(pB[i] + k0),
                                       (LAS u32*)&Bs[(tid + 256 * i) * 8], 16, 0, 0);
    }
    __syncthreads();
    {
      bf16x8 a[4], b[4];
#pragma unroll
      for (int i = 0; i < 4; ++i)
        a[i] = *(const bf16x8*)&As[((wm + i * 16 + lr) * 8 + sw0) * 8];
#pragma unroll
      for (int j = 0; j < 4; ++j)
        b[j] = *(const bf16x8*)&Bs[((wn + j * 16 + lr) * 8 + sw0) * 8];
#pragma unroll
      for (int i = 0; i < 4; ++i)
#pragma unroll
        for (int j = 0; j < 4; ++j)
          acc[i][j] = __builtin_amdgcn_mfma_f32_16x16x32_bf16(a[i], b[j], acc[i][j], 0, 0, 0);
#pragma unroll
      for (int i = 0; i < 4; ++i)
        a[i] = *(const bf16x8*)&As[((wm + i * 16 + lr) * 8 + sw1) * 8];
#pragma unroll
      for (int j = 0; j < 4; ++j)
        b[j] = *(const bf16x8*)&Bs[((wn + j * 16 + lr) * 8 + sw1) * 8];
#pragma unroll
      for (int i = 0; i < 4; ++i)
#pragma unroll
        for (int j = 0; j < 4; ++j)
          acc[i][j] = __builtin_amdgcn_mfma_f32_16x16x32_bf16(a[i], b[j], acc[i][j], 0, 0, 0);
    }
    __syncthreads();
  }

  float b1v[4];
#pragma unroll
  for (int ni = 0; ni < 4; ++ni)
    b1v[ni] = b1[task * HID + n0 + wn + ni * 16 + lr];
#pragma unroll
  for (int mi = 0; mi < 4; ++mi)
#pragma unroll
    for (int r = 0; r < 4; ++r) {
      const int row = wm + mi * 16 + quad * 4 + r;
#pragma unroll
      for (int ni = 0; ni < 4; ++ni) {
        float v = acc[mi][ni][r] + b1v[ni];
        v = v > 0.f ? v : 0.f;
        hS[row * 136 + wn + ni * 16 + lr] = f2bf(v);
      }
    }
  __syncthreads();

  const int cbase = (wave & 1) * 4;
  const unsigned short* pW2 =
      W2F + (((size_t)task * 8 + cbase) * 32 + by * 4) * 512 + lane * 8;

  f32x4 acc2[4][4];
#pragma unroll
  for (int mi = 0; mi < 4; ++mi)
#pragma unroll
    for (int ci = 0; ci < 4; ++ci) acc2[mi][ci] = (f32x4){0.f, 0.f, 0.f, 0.f};

#pragma unroll
  for (int e = 0; e < 4; ++e) {
    bf16x8 w2p[4], a2[4];
#pragma unroll
    for (int ci = 0; ci < 4; ++ci)
      w2p[ci] = *(const bf16x8*)(pW2 + ((size_t)ci * 32 + e) * 512);
#pragma unroll
    for (int mi = 0; mi < 4; ++mi)
      a2[mi] = *(const bf16x8*)&hS[(wm + mi * 16 + lr) * 136 + e * 32 + quad * 8];
#pragma unroll
    for (int mi = 0; mi < 4; ++mi)
#pragma unroll
      for (int ci = 0; ci < 4; ++ci)
        acc2[mi][ci] = __builtin_amdgcn_mfma_f32_16x16x32_bf16(
            a2[mi], w2p[ci], acc2[mi][ci], 0, 0, 0);
  }

  // Epilogue: f32 atomic accumulate into Out (b2 already there).
  // This wave's columns: col = wn + ci*16 + lr; skip col >= 100 and pad rows.
#pragma unroll
  for (int mi = 0; mi < 4; ++mi)
#pragma unroll
    for (int r = 0; r < 4; ++r) {
      const int row = wm + mi * 16 + quad * 4 + r;
      const int og  = ogS[row];
      if (og >= 0) {
        float* orow = Out + (size_t)og * NC;
#pragma unroll
        for (int ci = 0; ci < 4; ++ci) {
          const int col = wn + ci * 16 + lr;
          if (col < NC) atomicAdd(orow + col, acc2[mi][ci][r]);
        }
      }
    }
}

// ---------------------------------------------------------------------------
// Workspace layout (bytes) — total 37,814,272 used:
//   perm   int[9216]            @ 0           (36864)
//   starts int[9]               @ 37888
//   XP     bf16[9216*1024]      @ 65536       (18874368)
//   W1T    bf16[8*1024*1024]    @ 18939904    (16777216)
//   W2F    bf16[8*8*32*512]     @ 35717120    (2097152)   end 37814272
//   (Lp deleted in round 3 — gemm accumulates into Out directly)
// ---------------------------------------------------------------------------
extern "C" void kernel_launch(void* const* d_in, const int* in_sizes, int n_in,
                              void* d_out, int out_size, void* d_ws, size_t ws_size,
                              hipStream_t stream) {
  const float* x       = (const float*)d_in[0];
  const int*   task_id = (const int*)d_in[1];
  const float* W1      = (const float*)d_in[2];
  const float* b1      = (const float*)d_in[3];
  const float* W2      = (const float*)d_in[4];
  const float* b2      = (const float*)d_in[5];
  float* out = (float*)d_out;

  char* ws = (char*)d_ws;
  int* perm   = (int*)(ws + 0);
  int* starts = (int*)(ws + 37888);
  unsigned short* XP  = (unsigned short*)(ws + 65536);
  unsigned short* W1T = (unsigned short*)(ws + 18939904);
  unsigned short* W2F = (unsigned short*)(ws + 35717120);

  sortpre_k<<<SORT_BLKS + W1_BLKS + W2_BLKS + OUT_BLKS, 256, 0, stream>>>(
      task_id, W1, W1T, W2, W2F, b2, out, perm, starts);
  gather_k<<<MPAD, 256, 0, stream>>>(x, perm, XP);
  gemm_fused4<<<dim3(MPAD / 128, HID / 128), 256, 0, stream>>>(
      XP, W1T, W2F, b1, starts, perm, out);
}

// Round 6
// 147.410 us; speedup vs baseline: 1.1822x; 1.1822x over previous
//
#include <hip/hip_runtime.h>
#include <hip/hip_bf16.h>
#include <stdint.h>

// Problem constants (fixed by reference)
#define T_TASKS 8
#define DM      1024
#define HID     1024
#define NC      100
#define NCP     128
#define BATCH   8192
#define MPAD    9216      // 8192 + 8*128 worst-case 128-aligned padding

typedef __bf16 bf16x8 __attribute__((ext_vector_type(8)));
typedef float  f32x4  __attribute__((ext_vector_type(4)));
typedef unsigned int u32;
#define GAS __attribute__((address_space(1)))
#define LAS __attribute__((address_space(3)))

__device__ __forceinline__ unsigned short f2bf(float f) {
  __hip_bfloat16 h = __float2bfloat16(f);
  return __builtin_bit_cast(unsigned short, h);
}

__device__ __forceinline__ float bf2f(unsigned short u) {
  const u32 v = ((u32)u) << 16;
  return __builtin_bit_cast(float, v);
}

// ---------------------------------------------------------------------------
// sortpre_k: one launch, three roles (r2-proven structure).
//  [0, 32)       : sort -> perm/starts (each block redundantly computes
//                  totals+prefix from all 8192 task_ids; fills pads analytically)
//  [32, 2080)    : W1 [t][d][h] fp32 -> W1T [t][h][d] bf16 (vectorized)
//  [2080, 2208)  : W2 -> W2F fragment-packed bf16 (verified r5-r8)
// ---------------------------------------------------------------------------
#define SORT_BLKS 32
#define W1_BLKS (T_TASKS * 16 * 16)
#define W2_BLKS (16 * T_TASKS)
__global__ void sortpre_k(const int* __restrict__ task_id,
                          const float* __restrict__ W1,
                          unsigned short* __restrict__ W1T,
                          const float* __restrict__ W2,
                          unsigned short* __restrict__ W2F,
                          int* __restrict__ perm, int* __restrict__ starts) {
  __shared__ __align__(16) unsigned short tile[128 * 72];   // 18,432 B
  __shared__ int sAux[25];                                  // tot[8] prev[8] sst[9]
  const int bid = blockIdx.x;
  const int tid = threadIdx.x;

  if (bid < SORT_BLKS) {
    // ---- sort role ----
    int* hist = (int*)tile;            // [256][8] per-chunk histograms (8 KB)
    int* tot  = sAux;
    int* prev = sAux + 8;
    int* sst  = sAux + 16;             // 9 entries
#pragma unroll
    for (int t = 0; t < T_TASKS; ++t) hist[tid * 8 + t] = 0;
    __syncthreads();
    // chunk tid covers ids [tid*32, tid*32+32)
    const int cbase = tid * 32;
    for (int i = 0; i < 32; ++i) {
      const int t = task_id[cbase + i];
      hist[tid * 8 + t] += 1;
    }
    __syncthreads();
    if (tid < T_TASKS) {               // totals over all 256 chunks
      int s = 0;
      for (int r = 0; r < 256; ++r) s += hist[r * 8 + tid];
      tot[tid] = s;
    } else if (tid < 2 * T_TASKS) {    // prefix: chunks before this stripe
      const int t = tid - T_TASKS;
      const int lim = bid * 8;         // stripe [bid*256, ...) = chunks [bid*8, ...)
      int s = 0;
      for (int r = 0; r < lim; ++r) s += hist[r * 8 + t];
      prev[t] = s;
    }
    __syncthreads();
    if (tid == 0) {
      int off = 0;
      for (int t = 0; t < T_TASKS; ++t) { sst[t] = off; off += (tot[t] + 127) & ~127; }
      sst[T_TASKS] = off;
    }
    if (tid < T_TASKS) hist[tid] = 0;  // reuse as stripe slot counters
    __syncthreads();
    // scatter my 256 rows
    const int r = bid * 256 + tid;
    const int t = task_id[r];
    const int slot = atomicAdd(&hist[t], 1);
    perm[sst[t] + prev[t] + slot] = r;
    // pads: exactly MPAD-BATCH = 1024 positions never scattered-to
    if (tid < 32) {
      const int g = bid * 32 + tid;
      int acc = 0, pos = -1;
#pragma unroll
      for (int t2 = 0; t2 < T_TASKS; ++t2) {
        const int pc = sst[t2 + 1] - sst[t2] - tot[t2];
        if (pos < 0 && g < acc + pc) pos = sst[t2] + tot[t2] + (g - acc);
        acc += pc;
      }
      if (pos < 0) pos = sst[T_TASKS] + (g - acc);   // tail segment
      perm[pos] = -1;
    }
    if (bid == 0 && tid <= T_TASKS) starts[tid] = sst[tid];
    return;
  }

  if (bid < SORT_BLKS + W1_BLKS) {
    // ---- W1 transpose, vectorized global sides ----
    const int b  = bid - SORT_BLKS;
    const int t  = b >> 8;
    const int rem = b & 255;
    const int d0 = (rem >> 4) * 64;
    const int h0 = (rem & 15) * 64;
    const float* src = W1 + (size_t)t * DM * HID;
    unsigned short* dst = W1T + (size_t)t * HID * DM;
#pragma unroll
    for (int i = 0; i < 4; ++i) {
      const int idx = tid + 256 * i;           // 1024 float4 = 64d x 16 chunks
      const int d  = idx >> 4;
      const int hc = (idx & 15) * 4;
      const float4 f = *(const float4*)(src + (size_t)(d0 + d) * HID + h0 + hc);
      tile[(hc + 0) * 65 + d] = f2bf(f.x);
      tile[(hc + 1) * 65 + d] = f2bf(f.y);
      tile[(hc + 2) * 65 + d] = f2bf(f.z);
      tile[(hc + 3) * 65 + d] = f2bf(f.w);
    }
    __syncthreads();
#pragma unroll
    for (int i = 0; i < 2; ++i) {
      const int idx = tid + 256 * i;           // 512 ushort8 = 64h x 8 chunks
      const int lh  = idx >> 3;
      const int ldc = idx & 7;
      union { uint4 v; unsigned short s[8]; } o;
#pragma unroll
      for (int q = 0; q < 8; ++q) o.s[q] = tile[lh * 65 + ldc * 8 + q];
      *(uint4*)(dst + (size_t)(h0 + lh) * DM + d0 + ldc * 8) = o.v;
    }
    return;
  }

  // ---- W2 -> frag-packed W2F ----
  {
    const int b  = bid - (SORT_BLKS + W1_BLKS);
    const int t  = b >> 4;
    const int h0 = (b & 15) * 64;
    const float* src = W2 + (size_t)t * HID * NC;
#pragma unroll
    for (int i = 0; i < 36; ++i) tile[tid + 256 * i] = 0;
    __syncthreads();
#pragma unroll
    for (int i = 0; i < 32; ++i) {
      const int idx = tid + 256 * i;
      const int row = idx >> 7, col = idx & 127;
      if (col < NC)
        tile[col * 72 + row] = f2bf(src[(size_t)(h0 + row) * NC + col]);
    }
    __syncthreads();
    const int w = tid >> 6, lane = tid & 63;
    const int lr = lane & 15, quad = lane >> 4;
#pragma unroll
    for (int e = 0; e < 4; ++e) {
      const int fi = w * 4 + e;
      const int ci = fi >> 1, kcl = fi & 1;
      const uint4 v = *(const uint4*)&tile[(ci * 16 + lr) * 72 + kcl * 32 + quad * 8];
      unsigned short* dstp =
          W2F + (((size_t)t * 8 + ci) * 32 + (h0 >> 5) + kcl) * 512 + lane * 8;
      *(uint4*)dstp = v;
    }
  }
}

// ---------------------------------------------------------------------------
// gather_k: gather+convert x rows -> permuted bf16 XP (pads=0). grid MPAD.
// ---------------------------------------------------------------------------
__global__ void gather_k(const float* __restrict__ x,
                         const int* __restrict__ perm,
                         unsigned short* __restrict__ XP) {
  const int bid = blockIdx.x;
  const int tid = threadIdx.x;
  const int r = perm[bid];
  const int c = tid * 4;
  ushort4 v;
  if (r >= 0) {
    const float4 f = *(const float4*)(x + (size_t)r * DM + c);
    v.x = f2bf(f.x); v.y = f2bf(f.y); v.z = f2bf(f.z); v.w = f2bf(f.w);
  } else {
    v.x = 0; v.y = 0; v.z = 0; v.w = 0;
  }
  *(ushort4*)(XP + (size_t)bid * DM + c) = v;
}

// ---------------------------------------------------------------------------
// Fused MLP GEMM — round-5: EXACT r2 structure (known-good 149.4us run).
// Split-K in-kernel fixup withdrawn after 2x container failure (diagnostic
// A/B: if this passes, the fixup kernel is implicated; if this also fails,
// infra is sick). Only delta vs r2: skip the Lp store vector whose columns
// (112..127, wave&1==1, ci==3) are never read by reduce_k — dead-store
// elimination, uniform branch, -1/8 Lp write traffic.
// ---------------------------------------------------------------------------
__global__ __launch_bounds__(256, 3) void gemm_fused4(
    const unsigned short* __restrict__ XP,     // [MPAD][1024] bf16 permuted
    const unsigned short* __restrict__ W1T,    // [T][HID][1024] bf16
    const unsigned short* __restrict__ W2F,    // [T][8][32][512] frag-packed
    const float* __restrict__ b1,              // [T][HID]
    const int* __restrict__ starts,            // [9]
    unsigned short* __restrict__ Lp)           // [8][MPAD][128] bf16 partials
{
  __shared__ __align__(16) unsigned short lds[18432];  // 36,864 B
  unsigned short* As = lds;
  unsigned short* Bs = lds + 8192;
  unsigned short* hS = lds;                    // reuse: [128][136]

  const int tid = threadIdx.x;

  // XCD supertile swizzle: dispatch-linear L -> (bx, by); each XCD gets a
  // contiguous 9-wide bx chunk across all 8 by values (576 = 8 x 72 exact).
  const int L   = blockIdx.y * gridDim.x + blockIdx.x;  // x-fastest dispatch
  const int xcd = L & 7;
  const int idx = L >> 3;                                // 0..71
  const int bx  = xcd * 9 + (idx % 9);
  const int by  = idx / 9;

  const int p0  = bx * 128;
  const int n0  = by * 128;

  if (p0 >= starts[T_TASKS]) return;

  int task = 0;
#pragma unroll
  for (int t = 1; t < T_TASKS; ++t)
    if (p0 >= starts[t]) task = t;

  const int wave = tid >> 6;
  const int lane = tid & 63;
  const int wm   = (wave >> 1) * 64;
  const int wn   = (wave & 1) * 64;
  const int lr   = lane & 15;
  const int quad = lane >> 4;

  const int crow = tid >> 3;
  const int kc   = (tid & 7) ^ (crow & 7);
  const unsigned short* pA[4];
  const unsigned short* pB[4];
  const unsigned short* Bg = W1T + ((size_t)task * HID + n0) * 1024;
#pragma unroll
  for (int i = 0; i < 4; ++i) {
    const int row = crow + 32 * i;
    pA[i] = XP + (size_t)(p0 + row) * 1024 + kc * 8;
    pB[i] = Bg + (size_t)row * 1024 + kc * 8;
  }

  f32x4 acc[4][4];
#pragma unroll
  for (int i = 0; i < 4; ++i)
#pragma unroll
    for (int j = 0; j < 4; ++j) acc[i][j] = (f32x4){0.f, 0.f, 0.f, 0.f};

  const int sw0 = quad ^ (lr & 7);
  const int sw1 = (4 + quad) ^ (lr & 7);

  for (int k0 = 0; k0 < 1024; k0 += 64) {
#pragma unroll
    for (int i = 0; i < 4; ++i) {
      __builtin_amdgcn_global_load_lds((const GAS u32*)(pA[i] + k0),
                                       (LAS u32*)&As[(tid + 256 * i) * 8], 16, 0, 0);
      __builtin_amdgcn_global_load_lds((const GAS u32*)(pB[i] + k0),
                                       (LAS u32*)&Bs[(tid + 256 * i) * 8], 16, 0, 0);
    }
    __syncthreads();
    {
      bf16x8 a[4], b[4];
#pragma unroll
      for (int i = 0; i < 4; ++i)
        a[i] = *(const bf16x8*)&As[((wm + i * 16 + lr) * 8 + sw0) * 8];
#pragma unroll
      for (int j = 0; j < 4; ++j)
        b[j] = *(const bf16x8*)&Bs[((wn + j * 16 + lr) * 8 + sw0) * 8];
#pragma unroll
      for (int i = 0; i < 4; ++i)
#pragma unroll
        for (int j = 0; j < 4; ++j)
          acc[i][j] = __builtin_amdgcn_mfma_f32_16x16x32_bf16(a[i], b[j], acc[i][j], 0, 0, 0);
#pragma unroll
      for (int i = 0; i < 4; ++i)
        a[i] = *(const bf16x8*)&As[((wm + i * 16 + lr) * 8 + sw1) * 8];
#pragma unroll
      for (int j = 0; j < 4; ++j)
        b[j] = *(const bf16x8*)&Bs[((wn + j * 16 + lr) * 8 + sw1) * 8];
#pragma unroll
      for (int i = 0; i < 4; ++i)
#pragma unroll
        for (int j = 0; j < 4; ++j)
          acc[i][j] = __builtin_amdgcn_mfma_f32_16x16x32_bf16(a[i], b[j], acc[i][j], 0, 0, 0);
    }
    __syncthreads();
  }

  float b1v[4];
#pragma unroll
  for (int ni = 0; ni < 4; ++ni)
    b1v[ni] = b1[task * HID + n0 + wn + ni * 16 + lr];
#pragma unroll
  for (int mi = 0; mi < 4; ++mi)
#pragma unroll
    for (int r = 0; r < 4; ++r) {
      const int row = wm + mi * 16 + quad * 4 + r;
#pragma unroll
      for (int ni = 0; ni < 4; ++ni) {
        float v = acc[mi][ni][r] + b1v[ni];
        v = v > 0.f ? v : 0.f;
        hS[row * 136 + wn + ni * 16 + lr] = f2bf(v);
      }
    }
  __syncthreads();

  const int cbase = (wave & 1) * 4;
  const unsigned short* pW2 =
      W2F + (((size_t)task * 8 + cbase) * 32 + by * 4) * 512 + lane * 8;

  f32x4 acc2[4][4];
#pragma unroll
  for (int mi = 0; mi < 4; ++mi)
#pragma unroll
    for (int ci = 0; ci < 4; ++ci) acc2[mi][ci] = (f32x4){0.f, 0.f, 0.f, 0.f};

#pragma unroll
  for (int e = 0; e < 4; ++e) {
    bf16x8 w2p[4], a2[4];
#pragma unroll
    for (int ci = 0; ci < 4; ++ci)
      w2p[ci] = *(const bf16x8*)(pW2 + ((size_t)ci * 32 + e) * 512);
#pragma unroll
    for (int mi = 0; mi < 4; ++mi)
      a2[mi] = *(const bf16x8*)&hS[(wm + mi * 16 + lr) * 136 + e * 32 + quad * 8];
#pragma unroll
    for (int mi = 0; mi < 4; ++mi)
#pragma unroll
      for (int ci = 0; ci < 4; ++ci)
        acc2[mi][ci] = __builtin_amdgcn_mfma_f32_16x16x32_bf16(
            a2[mi], w2p[ci], acc2[mi][ci], 0, 0, 0);
  }

  unsigned short* lp = Lp + ((size_t)by * MPAD + p0) * NCP;
#pragma unroll
  for (int mi = 0; mi < 4; ++mi)
#pragma unroll
    for (int r = 0; r < 4; ++r) {
      const int row = wm + mi * 16 + quad * 4 + r;
#pragma unroll
      for (int ci = 0; ci < 4; ++ci) {
        // dead-store skip: cols 112..127 (wn==64, ci==3) never read by reduce_k
        if (wn + ci * 16 < NC)
          lp[row * NCP + wn + ci * 16 + lr] = f2bf(acc2[mi][ci][r]);
      }
    }
}

// ---------------------------------------------------------------------------
// reduce: sum 8 bf16 partial slices, +b2, scatter to out via perm (r2-exact).
// ---------------------------------------------------------------------------
__global__ void reduce_k(const unsigned short* __restrict__ Lp,
                         const int* __restrict__ perm,
                         const int* __restrict__ task_id,
                         const float* __restrict__ b2,
                         float* __restrict__ Out) {
  const int gid = blockIdx.x * 256 + threadIdx.x;
  const int row = gid >> 5;
  const int c4  = (gid & 31) * 4;
  if (c4 >= NC) return;
  const int og = perm[row];
  if (og < 0) return;
  float s0 = 0.f, s1 = 0.f, s2 = 0.f, s3 = 0.f;
#pragma unroll
  for (int sp = 0; sp < 8; ++sp) {
    const ushort4 v = *(const ushort4*)(Lp + ((size_t)sp * MPAD + row) * NCP + c4);
    s0 += bf2f(v.x); s1 += bf2f(v.y); s2 += bf2f(v.z); s3 += bf2f(v.w);
  }
  const int task = task_id[og];
  const float4 bb = *(const float4*)(b2 + (size_t)task * NC + c4);
  float4 o;
  o.x = s0 + bb.x; o.y = s1 + bb.y; o.z = s2 + bb.z; o.w = s3 + bb.w;
  *(float4*)(Out + (size_t)og * NC + c4) = o;
}

// ---------------------------------------------------------------------------
// Workspace layout (bytes) — total 56,688,640:
//   perm   int[9216]            @ 0           (36864)
//   starts int[9]               @ 37888
//   XP     bf16[9216*1024]      @ 65536       (18874368)
//   W1T    bf16[8*1024*1024]    @ 18939904    (16777216)
//   W2F    bf16[8*8*32*512]     @ 35717120    (2097152)
//   Lp     bf16[8*9216*128]     @ 37814272    (18874368)  end 56688640
// ---------------------------------------------------------------------------
extern "C" void kernel_launch(void* const* d_in, const int* in_sizes, int n_in,
                              void* d_out, int out_size, void* d_ws, size_t ws_size,
                              hipStream_t stream) {
  const float* x       = (const float*)d_in[0];
  const int*   task_id = (const int*)d_in[1];
  const float* W1      = (const float*)d_in[2];
  const float* b1      = (const float*)d_in[3];
  const float* W2      = (const float*)d_in[4];
  const float* b2      = (const float*)d_in[5];
  float* out = (float*)d_out;

  char* ws = (char*)d_ws;
  int* perm   = (int*)(ws + 0);
  int* starts = (int*)(ws + 37888);
  unsigned short* XP  = (unsigned short*)(ws + 65536);
  unsigned short* W1T = (unsigned short*)(ws + 18939904);
  unsigned short* W2F = (unsigned short*)(ws + 35717120);
  unsigned short* Lp  = (unsigned short*)(ws + 37814272);

  sortpre_k<<<SORT_BLKS + W1_BLKS + W2_BLKS, 256, 0, stream>>>(
      task_id, W1, W1T, W2, W2F, perm, starts);
  gather_k<<<MPAD, 256, 0, stream>>>(x, perm, XP);
  gemm_fused4<<<dim3(MPAD / 128, HID / 128), 256, 0, stream>>>(
      XP, W1T, W2F, b1, starts, Lp);
  reduce_k<<<MPAD * 32 / 256, 256, 0, stream>>>(Lp, perm, task_id, b2, out);
}

// Round 7
// 142.199 us; speedup vs baseline: 1.2255x; 1.0366x over previous
//
#include <hip/hip_runtime.h>
#include <hip/hip_bf16.h>
#include <stdint.h>

// Problem constants (fixed by reference)
#define T_TASKS 8
#define DM      1024
#define HID     1024
#define NC      100
#define NCP     128
#define BATCH   8192
#define MPAD    9216      // 8192 + 8*128 worst-case 128-aligned padding

typedef __bf16 bf16x8 __attribute__((ext_vector_type(8)));
typedef float  f32x4  __attribute__((ext_vector_type(4)));
typedef unsigned int u32;
#define GAS __attribute__((address_space(1)))
#define LAS __attribute__((address_space(3)))

__device__ __forceinline__ unsigned short f2bf(float f) {
  __hip_bfloat16 h = __float2bfloat16(f);
  return __builtin_bit_cast(unsigned short, h);
}

__device__ __forceinline__ float bf2f(unsigned short u) {
  const u32 v = ((u32)u) << 16;
  return __builtin_bit_cast(float, v);
}

// ---------------------------------------------------------------------------
// sortpre_k: one launch, four roles (round-7: adds in-order x->bf16 convert
// role XB; gather_k deleted — gemm stages A straight from XB via per-lane
// perm-derived global addresses, which global_load_lds supports).
//  [0, 32)       : sort -> perm/starts; block 0 also zeroes zrow
//  [32, 2080)    : W1 [t][d][h] fp32 -> W1T [t][h][d] bf16 (vectorized)
//  [2080, 2208)  : W2 -> W2F fragment-packed bf16 (verified)
//  [2208, 3232)  : XB[r][c] = bf16(x[r][c]) in ORIGINAL row order (no perm
//                  dependency; 8 rows/block, float4 loads / ushort4 stores)
// ---------------------------------------------------------------------------
#define SORT_BLKS 32
#define W1_BLKS (T_TASKS * 16 * 16)
#define W2_BLKS (16 * T_TASKS)
#define XB_BLKS (BATCH / 8)
__global__ void sortpre_k(const int* __restrict__ task_id,
                          const float* __restrict__ x,
                          const float* __restrict__ W1,
                          unsigned short* __restrict__ W1T,
                          const float* __restrict__ W2,
                          unsigned short* __restrict__ W2F,
                          unsigned short* __restrict__ XB,
                          unsigned short* __restrict__ zrow,
                          int* __restrict__ perm, int* __restrict__ starts) {
  __shared__ __align__(16) unsigned short tile[128 * 72];   // 18,432 B
  __shared__ int sAux[25];                                  // tot[8] prev[8] sst[9]
  const int bid = blockIdx.x;
  const int tid = threadIdx.x;

  if (bid < SORT_BLKS) {
    // ---- sort role ----
    int* hist = (int*)tile;            // [256][8] per-chunk histograms (8 KB)
    int* tot  = sAux;
    int* prev = sAux + 8;
    int* sst  = sAux + 16;             // 9 entries
    if (bid == 0) {                    // zero the 1024-elem zero-row (2 KB)
      ushort4 z; z.x = 0; z.y = 0; z.z = 0; z.w = 0;
      *(ushort4*)(zrow + tid * 4) = z;
    }
#pragma unroll
    for (int t = 0; t < T_TASKS; ++t) hist[tid * 8 + t] = 0;
    __syncthreads();
    // chunk tid covers ids [tid*32, tid*32+32)
    const int cbase = tid * 32;
    for (int i = 0; i < 32; ++i) {
      const int t = task_id[cbase + i];
      hist[tid * 8 + t] += 1;
    }
    __syncthreads();
    if (tid < T_TASKS) {               // totals over all 256 chunks
      int s = 0;
      for (int r = 0; r < 256; ++r) s += hist[r * 8 + tid];
      tot[tid] = s;
    } else if (tid < 2 * T_TASKS) {    // prefix: chunks before this stripe
      const int t = tid - T_TASKS;
      const int lim = bid * 8;         // stripe [bid*256, ...) = chunks [bid*8, ...)
      int s = 0;
      for (int r = 0; r < lim; ++r) s += hist[r * 8 + t];
      prev[t] = s;
    }
    __syncthreads();
    if (tid == 0) {
      int off = 0;
      for (int t = 0; t < T_TASKS; ++t) { sst[t] = off; off += (tot[t] + 127) & ~127; }
      sst[T_TASKS] = off;
    }
    if (tid < T_TASKS) hist[tid] = 0;  // reuse as stripe slot counters
    __syncthreads();
    // scatter my 256 rows
    const int r = bid * 256 + tid;
    const int t = task_id[r];
    const int slot = atomicAdd(&hist[t], 1);
    perm[sst[t] + prev[t] + slot] = r;
    // pads: exactly MPAD-BATCH = 1024 positions never scattered-to
    if (tid < 32) {
      const int g = bid * 32 + tid;
      int acc = 0, pos = -1;
#pragma unroll
      for (int t2 = 0; t2 < T_TASKS; ++t2) {
        const int pc = sst[t2 + 1] - sst[t2] - tot[t2];
        if (pos < 0 && g < acc + pc) pos = sst[t2] + tot[t2] + (g - acc);
        acc += pc;
      }
      if (pos < 0) pos = sst[T_TASKS] + (g - acc);   // tail segment
      perm[pos] = -1;
    }
    if (bid == 0 && tid <= T_TASKS) starts[tid] = sst[tid];
    return;
  }

  if (bid < SORT_BLKS + W1_BLKS) {
    // ---- W1 transpose, vectorized global sides ----
    const int b  = bid - SORT_BLKS;
    const int t  = b >> 8;
    const int rem = b & 255;
    const int d0 = (rem >> 4) * 64;
    const int h0 = (rem & 15) * 64;
    const float* src = W1 + (size_t)t * DM * HID;
    unsigned short* dst = W1T + (size_t)t * HID * DM;
#pragma unroll
    for (int i = 0; i < 4; ++i) {
      const int idx = tid + 256 * i;           // 1024 float4 = 64d x 16 chunks
      const int d  = idx >> 4;
      const int hc = (idx & 15) * 4;
      const float4 f = *(const float4*)(src + (size_t)(d0 + d) * HID + h0 + hc);
      tile[(hc + 0) * 65 + d] = f2bf(f.x);
      tile[(hc + 1) * 65 + d] = f2bf(f.y);
      tile[(hc + 2) * 65 + d] = f2bf(f.z);
      tile[(hc + 3) * 65 + d] = f2bf(f.w);
    }
    __syncthreads();
#pragma unroll
    for (int i = 0; i < 2; ++i) {
      const int idx = tid + 256 * i;           // 512 ushort8 = 64h x 8 chunks
      const int lh  = idx >> 3;
      const int ldc = idx & 7;
      union { uint4 v; unsigned short s[8]; } o;
#pragma unroll
      for (int q = 0; q < 8; ++q) o.s[q] = tile[lh * 65 + ldc * 8 + q];
      *(uint4*)(dst + (size_t)(h0 + lh) * DM + d0 + ldc * 8) = o.v;
    }
    return;
  }

  if (bid < SORT_BLKS + W1_BLKS + W2_BLKS) {
    // ---- W2 -> frag-packed W2F ----
    const int b  = bid - (SORT_BLKS + W1_BLKS);
    const int t  = b >> 4;
    const int h0 = (b & 15) * 64;
    const float* src = W2 + (size_t)t * HID * NC;
#pragma unroll
    for (int i = 0; i < 36; ++i) tile[tid + 256 * i] = 0;
    __syncthreads();
#pragma unroll
    for (int i = 0; i < 32; ++i) {
      const int idx = tid + 256 * i;
      const int row = idx >> 7, col = idx & 127;
      if (col < NC)
        tile[col * 72 + row] = f2bf(src[(size_t)(h0 + row) * NC + col]);
    }
    __syncthreads();
    const int w = tid >> 6, lane = tid & 63;
    const int lr = lane & 15, quad = lane >> 4;
#pragma unroll
    for (int e = 0; e < 4; ++e) {
      const int fi = w * 4 + e;
      const int ci = fi >> 1, kcl = fi & 1;
      const uint4 v = *(const uint4*)&tile[(ci * 16 + lr) * 72 + kcl * 32 + quad * 8];
      unsigned short* dstp =
          W2F + (((size_t)t * 8 + ci) * 32 + (h0 >> 5) + kcl) * 512 + lane * 8;
      *(uint4*)dstp = v;
    }
    return;
  }

  // ---- XB: in-order x -> bf16 convert (no perm dependency) ----
  {
    const int b   = bid - (SORT_BLKS + W1_BLKS + W2_BLKS);
    const int row = b * 8 + (tid >> 5);
    const int l   = (tid & 31) * 4;
    const float* src = x + (size_t)row * DM;
    unsigned short* dst = XB + (size_t)row * DM;
#pragma unroll
    for (int j = 0; j < 8; ++j) {
      const int c = l + j * 128;                 // 32 lanes x 16B contiguous
      const float4 f = *(const float4*)(src + c);
      ushort4 v;
      v.x = f2bf(f.x); v.y = f2bf(f.y); v.z = f2bf(f.z); v.w = f2bf(f.w);
      *(ushort4*)(dst + c) = v;
    }
  }
}

// ---------------------------------------------------------------------------
// Fused MLP GEMM — round-7: A staged DIRECTLY from in-order XB using per-lane
// perm-derived global source addresses (global_load_lds's global side is
// per-lane — m173/HK pattern). Pad rows read a zeroed 2KB row. Rest of the
// structure identical to the r6-proven kernel (incl. dead-store skip).
// ---------------------------------------------------------------------------
__global__ __launch_bounds__(256, 3) void gemm_fused4(
    const unsigned short* __restrict__ XB,     // [BATCH][1024] bf16 in-order
    const unsigned short* __restrict__ W1T,    // [T][HID][1024] bf16
    const unsigned short* __restrict__ W2F,    // [T][8][32][512] frag-packed
    const float* __restrict__ b1,              // [T][HID]
    const int* __restrict__ starts,            // [9]
    const int* __restrict__ perm,              // [MPAD]
    const unsigned short* __restrict__ zrow,   // [1024] zeros
    unsigned short* __restrict__ Lp)           // [8][MPAD][128] bf16 partials
{
  __shared__ __align__(16) unsigned short lds[18432];  // 36,864 B
  unsigned short* As = lds;
  unsigned short* Bs = lds + 8192;
  unsigned short* hS = lds;                    // reuse: [128][136]

  const int tid = threadIdx.x;

  // XCD supertile swizzle: dispatch-linear L -> (bx, by); each XCD gets a
  // contiguous 9-wide bx chunk across all 8 by values (576 = 8 x 72 exact).
  const int L   = blockIdx.y * gridDim.x + blockIdx.x;  // x-fastest dispatch
  const int xcd = L & 7;
  const int idx = L >> 3;                                // 0..71
  const int bx  = xcd * 9 + (idx % 9);
  const int by  = idx / 9;

  const int p0  = bx * 128;
  const int n0  = by * 128;

  if (p0 >= starts[T_TASKS]) return;

  int task = 0;
#pragma unroll
  for (int t = 1; t < T_TASKS; ++t)
    if (p0 >= starts[t]) task = t;

  const int wave = tid >> 6;
  const int lane = tid & 63;
  const int wm   = (wave >> 1) * 64;
  const int wn   = (wave & 1) * 64;
  const int lr   = lane & 15;
  const int quad = lane >> 4;

  const int crow = tid >> 3;
  const int kc   = (tid & 7) ^ (crow & 7);
  const unsigned short* pA[4];
  const unsigned short* pB[4];
  const unsigned short* Bg = W1T + ((size_t)task * HID + n0) * 1024;
#pragma unroll
  for (int i = 0; i < 4; ++i) {
    const int row = crow + 32 * i;
    const int og  = perm[p0 + row];
    const unsigned short* base = (og >= 0) ? (XB + (size_t)og * 1024) : zrow;
    pA[i] = base + kc * 8;
    pB[i] = Bg + (size_t)row * 1024 + kc * 8;
  }

  f32x4 acc[4][4];
#pragma unroll
  for (int i = 0; i < 4; ++i)
#pragma unroll
    for (int j = 0; j < 4; ++j) acc[i][j] = (f32x4){0.f, 0.f, 0.f, 0.f};

  const int sw0 = quad ^ (lr & 7);
  const int sw1 = (4 + quad) ^ (lr & 7);

  for (int k0 = 0; k0 < 1024; k0 += 64) {
#pragma unroll
    for (int i = 0; i < 4; ++i) {
      __builtin_amdgcn_global_load_lds((const GAS u32*)(pA[i] + k0),
                                       (LAS u32*)&As[(tid + 256 * i) * 8], 16, 0, 0);
      __builtin_amdgcn_global_load_lds((const GAS u32*)(pB[i] + k0),
                                       (LAS u32*)&Bs[(tid + 256 * i) * 8], 16, 0, 0);
    }
    __syncthreads();
    {
      bf16x8 a[4], b[4];
#pragma unroll
      for (int i = 0; i < 4; ++i)
        a[i] = *(const bf16x8*)&As[((wm + i * 16 + lr) * 8 + sw0) * 8];
#pragma unroll
      for (int j = 0; j < 4; ++j)
        b[j] = *(const bf16x8*)&Bs[((wn + j * 16 + lr) * 8 + sw0) * 8];
#pragma unroll
      for (int i = 0; i < 4; ++i)
#pragma unroll
        for (int j = 0; j < 4; ++j)
          acc[i][j] = __builtin_amdgcn_mfma_f32_16x16x32_bf16(a[i], b[j], acc[i][j], 0, 0, 0);
#pragma unroll
      for (int i = 0; i < 4; ++i)
        a[i] = *(const bf16x8*)&As[((wm + i * 16 + lr) * 8 + sw1) * 8];
#pragma unroll
      for (int j = 0; j < 4; ++j)
        b[j] = *(const bf16x8*)&Bs[((wn + j * 16 + lr) * 8 + sw1) * 8];
#pragma unroll
      for (int i = 0; i < 4; ++i)
#pragma unroll
        for (int j = 0; j < 4; ++j)
          acc[i][j] = __builtin_amdgcn_mfma_f32_16x16x32_bf16(a[i], b[j], acc[i][j], 0, 0, 0);
    }
    __syncthreads();
  }

  float b1v[4];
#pragma unroll
  for (int ni = 0; ni < 4; ++ni)
    b1v[ni] = b1[task * HID + n0 + wn + ni * 16 + lr];
#pragma unroll
  for (int mi = 0; mi < 4; ++mi)
#pragma unroll
    for (int r = 0; r < 4; ++r) {
      const int row = wm + mi * 16 + quad * 4 + r;
#pragma unroll
      for (int ni = 0; ni < 4; ++ni) {
        float v = acc[mi][ni][r] + b1v[ni];
        v = v > 0.f ? v : 0.f;
        hS[row * 136 + wn + ni * 16 + lr] = f2bf(v);
      }
    }
  __syncthreads();

  const int cbase = (wave & 1) * 4;
  const unsigned short* pW2 =
      W2F + (((size_t)task * 8 + cbase) * 32 + by * 4) * 512 + lane * 8;

  f32x4 acc2[4][4];
#pragma unroll
  for (int mi = 0; mi < 4; ++mi)
#pragma unroll
    for (int ci = 0; ci < 4; ++ci) acc2[mi][ci] = (f32x4){0.f, 0.f, 0.f, 0.f};

#pragma unroll
  for (int e = 0; e < 4; ++e) {
    bf16x8 w2p[4], a2[4];
#pragma unroll
    for (int ci = 0; ci < 4; ++ci)
      w2p[ci] = *(const bf16x8*)(pW2 + ((size_t)ci * 32 + e) * 512);
#pragma unroll
    for (int mi = 0; mi < 4; ++mi)
      a2[mi] = *(const bf16x8*)&hS[(wm + mi * 16 + lr) * 136 + e * 32 + quad * 8];
#pragma unroll
    for (int mi = 0; mi < 4; ++mi)
#pragma unroll
      for (int ci = 0; ci < 4; ++ci)
        acc2[mi][ci] = __builtin_amdgcn_mfma_f32_16x16x32_bf16(
            a2[mi], w2p[ci], acc2[mi][ci], 0, 0, 0);
  }

  unsigned short* lp = Lp + ((size_t)by * MPAD + p0) * NCP;
#pragma unroll
  for (int mi = 0; mi < 4; ++mi)
#pragma unroll
    for (int r = 0; r < 4; ++r) {
      const int row = wm + mi * 16 + quad * 4 + r;
#pragma unroll
      for (int ci = 0; ci < 4; ++ci) {
        // dead-store skip: cols 112..127 (wn==64, ci==3) never read by reduce_k
        if (wn + ci * 16 < NC)
          lp[row * NCP + wn + ci * 16 + lr] = f2bf(acc2[mi][ci][r]);
      }
    }
}

// ---------------------------------------------------------------------------
// reduce: sum 8 bf16 partial slices, +b2, scatter to out via perm (r2-exact).
// ---------------------------------------------------------------------------
__global__ void reduce_k(const unsigned short* __restrict__ Lp,
                         const int* __restrict__ perm,
                         const int* __restrict__ task_id,
                         const float* __restrict__ b2,
                         float* __restrict__ Out) {
  const int gid = blockIdx.x * 256 + threadIdx.x;
  const int row = gid >> 5;
  const int c4  = (gid & 31) * 4;
  if (c4 >= NC) return;
  const int og = perm[row];
  if (og < 0) return;
  float s0 = 0.f, s1 = 0.f, s2 = 0.f, s3 = 0.f;
#pragma unroll
  for (int sp = 0; sp < 8; ++sp) {
    const ushort4 v = *(const ushort4*)(Lp + ((size_t)sp * MPAD + row) * NCP + c4);
    s0 += bf2f(v.x); s1 += bf2f(v.y); s2 += bf2f(v.z); s3 += bf2f(v.w);
  }
  const int task = task_id[og];
  const float4 bb = *(const float4*)(b2 + (size_t)task * NC + c4);
  float4 o;
  o.x = s0 + bb.x; o.y = s1 + bb.y; o.z = s2 + bb.z; o.w = s3 + bb.w;
  *(float4*)(Out + (size_t)og * NC + c4) = o;
}

// ---------------------------------------------------------------------------
// Workspace layout (bytes) — total 56,688,640 (unchanged):
//   perm   int[9216]            @ 0           (36864)
//   starts int[9]               @ 37888
//   zrow   bf16[1024]           @ 40960       (2048)
//   XB     bf16[8192*1024]      @ 65536       (16777216)  [in old XP slot]
//   W1T    bf16[8*1024*1024]    @ 18939904    (16777216)
//   W2F    bf16[8*8*32*512]     @ 35717120    (2097152)
//   Lp     bf16[8*9216*128]     @ 37814272    (18874368)  end 56688640
// ---------------------------------------------------------------------------
extern "C" void kernel_launch(void* const* d_in, const int* in_sizes, int n_in,
                              void* d_out, int out_size, void* d_ws, size_t ws_size,
                              hipStream_t stream) {
  const float* x       = (const float*)d_in[0];
  const int*   task_id = (const int*)d_in[1];
  const float* W1      = (const float*)d_in[2];
  const float* b1      = (const float*)d_in[3];
  const float* W2      = (const float*)d_in[4];
  const float* b2      = (const float*)d_in[5];
  float* out = (float*)d_out;

  char* ws = (char*)d_ws;
  int* perm   = (int*)(ws + 0);
  int* starts = (int*)(ws + 37888);
  unsigned short* zrow = (unsigned short*)(ws + 40960);
  unsigned short* XB  = (unsigned short*)(ws + 65536);
  unsigned short* W1T = (unsigned short*)(ws + 18939904);
  unsigned short* W2F = (unsigned short*)(ws + 35717120);
  unsigned short* Lp  = (unsigned short*)(ws + 37814272);

  sortpre_k<<<SORT_BLKS + W1_BLKS + W2_BLKS + XB_BLKS, 256, 0, stream>>>(
      task_id, x, W1, W1T, W2, W2F, XB, zrow, perm, starts);
  gemm_fused4<<<dim3(MPAD / 128, HID / 128), 256, 0, stream>>>(
      XB, W1T, W2F, b1, starts, perm, zrow, Lp);
  reduce_k<<<MPAD * 32 / 256, 256, 0, stream>>>(Lp, perm, task_id, b2, out);
}

// Round 9
// 140.834 us; speedup vs baseline: 1.2374x; 1.0097x over previous
//
#include <hip/hip_runtime.h>
#include <hip/hip_bf16.h>
#include <stdint.h>

// Problem constants (fixed by reference)
#define T_TASKS 8
#define DM      1024
#define HID     1024
#define NC      100
#define NCP     128
#define BATCH   8192
#define MPAD    9216      // 8192 + 8*128 worst-case 128-aligned padding

typedef __bf16 bf16x8 __attribute__((ext_vector_type(8)));
typedef float  f32x4  __attribute__((ext_vector_type(4)));
typedef unsigned int u32;
#define GAS __attribute__((address_space(1)))
#define LAS __attribute__((address_space(3)))

__device__ __forceinline__ unsigned short f2bf(float f) {
  __hip_bfloat16 h = __float2bfloat16(f);
  return __builtin_bit_cast(unsigned short, h);
}

__device__ __forceinline__ float bf2f(unsigned short u) {
  const u32 v = ((u32)u) << 16;
  return __builtin_bit_cast(float, v);
}

// ---------------------------------------------------------------------------
// sortpre_k: one launch, four roles (r7-proven).
//  [0, 32)       : sort -> perm/starts; block 0 also zeroes zrow
//  [32, 2080)    : W1 [t][d][h] fp32 -> W1T [t][h][d] bf16 (vectorized)
//  [2080, 2208)  : W2 -> W2F fragment-packed bf16 (verified)
//  [2208, 3232)  : XB[r][c] = bf16(x[r][c]) in ORIGINAL row order
// ---------------------------------------------------------------------------
#define SORT_BLKS 32
#define W1_BLKS (T_TASKS * 16 * 16)
#define W2_BLKS (16 * T_TASKS)
#define XB_BLKS (BATCH / 8)
__global__ void sortpre_k(const int* __restrict__ task_id,
                          const float* __restrict__ x,
                          const float* __restrict__ W1,
                          unsigned short* __restrict__ W1T,
                          const float* __restrict__ W2,
                          unsigned short* __restrict__ W2F,
                          unsigned short* __restrict__ XB,
                          unsigned short* __restrict__ zrow,
                          int* __restrict__ perm, int* __restrict__ starts) {
  __shared__ __align__(16) unsigned short tile[128 * 72];   // 18,432 B
  __shared__ int sAux[25];                                  // tot[8] prev[8] sst[9]
  const int bid = blockIdx.x;
  const int tid = threadIdx.x;

  if (bid < SORT_BLKS) {
    // ---- sort role ----
    int* hist = (int*)tile;            // [256][8] per-chunk histograms (8 KB)
    int* tot  = sAux;
    int* prev = sAux + 8;
    int* sst  = sAux + 16;             // 9 entries
    if (bid == 0) {                    // zero the 1024-elem zero-row (2 KB)
      ushort4 z; z.x = 0; z.y = 0; z.z = 0; z.w = 0;
      *(ushort4*)(zrow + tid * 4) = z;
    }
#pragma unroll
    for (int t = 0; t < T_TASKS; ++t) hist[tid * 8 + t] = 0;
    __syncthreads();
    // chunk tid covers ids [tid*32, tid*32+32)
    const int cbase = tid * 32;
    for (int i = 0; i < 32; ++i) {
      const int t = task_id[cbase + i];
      hist[tid * 8 + t] += 1;
    }
    __syncthreads();
    if (tid < T_TASKS) {               // totals over all 256 chunks
      int s = 0;
      for (int r = 0; r < 256; ++r) s += hist[r * 8 + tid];
      tot[tid] = s;
    } else if (tid < 2 * T_TASKS) {    // prefix: chunks before this stripe
      const int t = tid - T_TASKS;
      const int lim = bid * 8;         // stripe [bid*256, ...) = chunks [bid*8, ...)
      int s = 0;
      for (int r = 0; r < lim; ++r) s += hist[r * 8 + t];
      prev[t] = s;
    }
    __syncthreads();
    if (tid == 0) {
      int off = 0;
      for (int t = 0; t < T_TASKS; ++t) { sst[t] = off; off += (tot[t] + 127) & ~127; }
      sst[T_TASKS] = off;
    }
    if (tid < T_TASKS) hist[tid] = 0;  // reuse as stripe slot counters
    __syncthreads();
    // scatter my 256 rows
    const int r = bid * 256 + tid;
    const int t = task_id[r];
    const int slot = atomicAdd(&hist[t], 1);
    perm[sst[t] + prev[t] + slot] = r;
    // pads: exactly MPAD-BATCH = 1024 positions never scattered-to
    if (tid < 32) {
      const int g = bid * 32 + tid;
      int acc = 0, pos = -1;
#pragma unroll
      for (int t2 = 0; t2 < T_TASKS; ++t2) {
        const int pc = sst[t2 + 1] - sst[t2] - tot[t2];
        if (pos < 0 && g < acc + pc) pos = sst[t2] + tot[t2] + (g - acc);
        acc += pc;
      }
      if (pos < 0) pos = sst[T_TASKS] + (g - acc);   // tail segment
      perm[pos] = -1;
    }
    if (bid == 0 && tid <= T_TASKS) starts[tid] = sst[tid];
    return;
  }

  if (bid < SORT_BLKS + W1_BLKS) {
    // ---- W1 transpose, vectorized global sides ----
    const int b  = bid - SORT_BLKS;
    const int t  = b >> 8;
    const int rem = b & 255;
    const int d0 = (rem >> 4) * 64;
    const int h0 = (rem & 15) * 64;
    const float* src = W1 + (size_t)t * DM * HID;
    unsigned short* dst = W1T + (size_t)t * HID * DM;
#pragma unroll
    for (int i = 0; i < 4; ++i) {
      const int idx = tid + 256 * i;           // 1024 float4 = 64d x 16 chunks
      const int d  = idx >> 4;
      const int hc = (idx & 15) * 4;
      const float4 f = *(const float4*)(src + (size_t)(d0 + d) * HID + h0 + hc);
      tile[(hc + 0) * 65 + d] = f2bf(f.x);
      tile[(hc + 1) * 65 + d] = f2bf(f.y);
      tile[(hc + 2) * 65 + d] = f2bf(f.z);
      tile[(hc + 3) * 65 + d] = f2bf(f.w);
    }
    __syncthreads();
#pragma unroll
    for (int i = 0; i < 2; ++i) {
      const int idx = tid + 256 * i;           // 512 ushort8 = 64h x 8 chunks
      const int lh  = idx >> 3;
      const int ldc = idx & 7;
      union { uint4 v; unsigned short s[8]; } o;
#pragma unroll
      for (int q = 0; q < 8; ++q) o.s[q] = tile[lh * 65 + ldc * 8 + q];
      *(uint4*)(dst + (size_t)(h0 + lh) * DM + d0 + ldc * 8) = o.v;
    }
    return;
  }

  if (bid < SORT_BLKS + W1_BLKS + W2_BLKS) {
    // ---- W2 -> frag-packed W2F ----
    const int b  = bid - (SORT_BLKS + W1_BLKS);
    const int t  = b >> 4;
    const int h0 = (b & 15) * 64;
    const float* src = W2 + (size_t)t * HID * NC;
#pragma unroll
    for (int i = 0; i < 36; ++i) tile[tid + 256 * i] = 0;
    __syncthreads();
#pragma unroll
    for (int i = 0; i < 32; ++i) {
      const int idx = tid + 256 * i;
      const int row = idx >> 7, col = idx & 127;
      if (col < NC)
        tile[col * 72 + row] = f2bf(src[(size_t)(h0 + row) * NC + col]);
    }
    __syncthreads();
    const int w = tid >> 6, lane = tid & 63;
    const int lr = lane & 15, quad = lane >> 4;
#pragma unroll
    for (int e = 0; e < 4; ++e) {
      const int fi = w * 4 + e;
      const int ci = fi >> 1, kcl = fi & 1;
      const uint4 v = *(const uint4*)&tile[(ci * 16 + lr) * 72 + kcl * 32 + quad * 8];
      unsigned short* dstp =
          W2F + (((size_t)t * 8 + ci) * 32 + (h0 >> 5) + kcl) * 512 + lane * 8;
      *(uint4*)dstp = v;
    }
    return;
  }

  // ---- XB: in-order x -> bf16 convert (no perm dependency) ----
  {
    const int b   = bid - (SORT_BLKS + W1_BLKS + W2_BLKS);
    const int row = b * 8 + (tid >> 5);
    const int l   = (tid & 31) * 4;
    const float* src = x + (size_t)row * DM;
    unsigned short* dst = XB + (size_t)row * DM;
#pragma unroll
    for (int j = 0; j < 8; ++j) {
      const int c = l + j * 128;                 // 32 lanes x 16B contiguous
      const float4 f = *(const float4*)(src + c);
      ushort4 v;
      v.x = f2bf(f.x); v.y = f2bf(f.y); v.z = f2bf(f.z); v.w = f2bf(f.w);
      *(ushort4*)(dst + c) = v;
    }
  }
}

// ---------------------------------------------------------------------------
// Fused MLP GEMM — round-9: exact r7 body (perm-indirect A staging via
// per-lane global_load_lds source addresses; proven 142.2us), with the Lp
// dead-store predicate tightened from group-level (wn+ci*16<NC) to per-lane
// (col<NC): scalar u16 stores are exec-masked, so cols 100..111 now also
// skipped — -12/112 Lp write traffic, zero structural risk.
// Cooperative/atomic/counter reduce-fusion all empirically dead in this
// harness (r3: 3.4ns/atomic; r4/r5: container kills; r8: coop launch not
// capturable -> kernel never ran). reduce_k stays.
// ---------------------------------------------------------------------------
__global__ __launch_bounds__(256, 3) void gemm_fused4(
    const unsigned short* __restrict__ XB,     // [BATCH][1024] bf16 in-order
    const unsigned short* __restrict__ W1T,    // [T][HID][1024] bf16
    const unsigned short* __restrict__ W2F,    // [T][8][32][512] frag-packed
    const float* __restrict__ b1,              // [T][HID]
    const int* __restrict__ starts,            // [9]
    const int* __restrict__ perm,              // [MPAD]
    const unsigned short* __restrict__ zrow,   // [1024] zeros
    unsigned short* __restrict__ Lp)           // [8][MPAD][128] bf16 partials
{
  __shared__ __align__(16) unsigned short lds[18432];  // 36,864 B
  unsigned short* As = lds;
  unsigned short* Bs = lds + 8192;
  unsigned short* hS = lds;                    // reuse: [128][136]

  const int tid = threadIdx.x;

  // XCD supertile swizzle: dispatch-linear L -> (bx, by); each XCD gets a
  // contiguous 9-wide bx chunk across all 8 by values (576 = 8 x 72 exact).
  const int L   = blockIdx.y * gridDim.x + blockIdx.x;  // x-fastest dispatch
  const int xcd = L & 7;
  const int idx = L >> 3;                                // 0..71
  const int bx  = xcd * 9 + (idx % 9);
  const int by  = idx / 9;

  const int p0  = bx * 128;
  const int n0  = by * 128;

  if (p0 >= starts[T_TASKS]) return;

  int task = 0;
#pragma unroll
  for (int t = 1; t < T_TASKS; ++t)
    if (p0 >= starts[t]) task = t;

  const int wave = tid >> 6;
  const int lane = tid & 63;
  const int wm   = (wave >> 1) * 64;
  const int wn   = (wave & 1) * 64;
  const int lr   = lane & 15;
  const int quad = lane >> 4;

  const int crow = tid >> 3;
  const int kc   = (tid & 7) ^ (crow & 7);
  const unsigned short* pA[4];
  const unsigned short* pB[4];
  const unsigned short* Bg = W1T + ((size_t)task * HID + n0) * 1024;
#pragma unroll
  for (int i = 0; i < 4; ++i) {
    const int row = crow + 32 * i;
    const int og  = perm[p0 + row];
    const unsigned short* base = (og >= 0) ? (XB + (size_t)og * 1024) : zrow;
    pA[i] = base + kc * 8;
    pB[i] = Bg + (size_t)row * 1024 + kc * 8;
  }

  f32x4 acc[4][4];
#pragma unroll
  for (int i = 0; i < 4; ++i)
#pragma unroll
    for (int j = 0; j < 4; ++j) acc[i][j] = (f32x4){0.f, 0.f, 0.f, 0.f};

  const int sw0 = quad ^ (lr & 7);
  const int sw1 = (4 + quad) ^ (lr & 7);

  for (int k0 = 0; k0 < 1024; k0 += 64) {
#pragma unroll
    for (int i = 0; i < 4; ++i) {
      __builtin_amdgcn_global_load_lds((const GAS u32*)(pA[i] + k0),
                                       (LAS u32*)&As[(tid + 256 * i) * 8], 16, 0, 0);
      __builtin_amdgcn_global_load_lds((const GAS u32*)(pB[i] + k0),
                                       (LAS u32*)&Bs[(tid + 256 * i) * 8], 16, 0, 0);
    }
    __syncthreads();
    {
      bf16x8 a[4], b[4];
#pragma unroll
      for (int i = 0; i < 4; ++i)
        a[i] = *(const bf16x8*)&As[((wm + i * 16 + lr) * 8 + sw0) * 8];
#pragma unroll
      for (int j = 0; j < 4; ++j)
        b[j] = *(const bf16x8*)&Bs[((wn + j * 16 + lr) * 8 + sw0) * 8];
#pragma unroll
      for (int i = 0; i < 4; ++i)
#pragma unroll
        for (int j = 0; j < 4; ++j)
          acc[i][j] = __builtin_amdgcn_mfma_f32_16x16x32_bf16(a[i], b[j], acc[i][j], 0, 0, 0);
#pragma unroll
      for (int i = 0; i < 4; ++i)
        a[i] = *(const bf16x8*)&As[((wm + i * 16 + lr) * 8 + sw1) * 8];
#pragma unroll
      for (int j = 0; j < 4; ++j)
        b[j] = *(const bf16x8*)&Bs[((wn + j * 16 + lr) * 8 + sw1) * 8];
#pragma unroll
      for (int i = 0; i < 4; ++i)
#pragma unroll
        for (int j = 0; j < 4; ++j)
          acc[i][j] = __builtin_amdgcn_mfma_f32_16x16x32_bf16(a[i], b[j], acc[i][j], 0, 0, 0);
    }
    __syncthreads();
  }

  float b1v[4];
#pragma unroll
  for (int ni = 0; ni < 4; ++ni)
    b1v[ni] = b1[task * HID + n0 + wn + ni * 16 + lr];
#pragma unroll
  for (int mi = 0; mi < 4; ++mi)
#pragma unroll
    for (int r = 0; r < 4; ++r) {
      const int row = wm + mi * 16 + quad * 4 + r;
#pragma unroll
      for (int ni = 0; ni < 4; ++ni) {
        float v = acc[mi][ni][r] + b1v[ni];
        v = v > 0.f ? v : 0.f;
        hS[row * 136 + wn + ni * 16 + lr] = f2bf(v);
      }
    }
  __syncthreads();

  const int cbase = (wave & 1) * 4;
  const unsigned short* pW2 =
      W2F + (((size_t)task * 8 + cbase) * 32 + by * 4) * 512 + lane * 8;

  f32x4 acc2[4][4];
#pragma unroll
  for (int mi = 0; mi < 4; ++mi)
#pragma unroll
    for (int ci = 0; ci < 4; ++ci) acc2[mi][ci] = (f32x4){0.f, 0.f, 0.f, 0.f};

#pragma unroll
  for (int e = 0; e < 4; ++e) {
    bf16x8 w2p[4], a2[4];
#pragma unroll
    for (int ci = 0; ci < 4; ++ci)
      w2p[ci] = *(const bf16x8*)(pW2 + ((size_t)ci * 32 + e) * 512);
#pragma unroll
    for (int mi = 0; mi < 4; ++mi)
      a2[mi] = *(const bf16x8*)&hS[(wm + mi * 16 + lr) * 136 + e * 32 + quad * 8];
#pragma unroll
    for (int mi = 0; mi < 4; ++mi)
#pragma unroll
      for (int ci = 0; ci < 4; ++ci)
        acc2[mi][ci] = __builtin_amdgcn_mfma_f32_16x16x32_bf16(
            a2[mi], w2p[ci], acc2[mi][ci], 0, 0, 0);
  }

  unsigned short* lp = Lp + ((size_t)by * MPAD + p0) * NCP;
#pragma unroll
  for (int mi = 0; mi < 4; ++mi)
#pragma unroll
    for (int r = 0; r < 4; ++r) {
      const int row = wm + mi * 16 + quad * 4 + r;
#pragma unroll
      for (int ci = 0; ci < 4; ++ci) {
        const int col = wn + ci * 16 + lr;
        // per-lane dead-store skip: cols >= 100 never read by reduce_k
        if (col < NC)
          lp[row * NCP + col] = f2bf(acc2[mi][ci][r]);
      }
    }
}

// ---------------------------------------------------------------------------
// reduce: sum 8 bf16 partial slices, +b2, scatter to out via perm (r2-exact).
// ---------------------------------------------------------------------------
__global__ void reduce_k(const unsigned short* __restrict__ Lp,
                         const int* __restrict__ perm,
                         const int* __restrict__ task_id,
                         const float* __restrict__ b2,
                         float* __restrict__ Out) {
  const int gid = blockIdx.x * 256 + threadIdx.x;
  const int row = gid >> 5;
  const int c4  = (gid & 31) * 4;
  if (c4 >= NC) return;
  const int og = perm[row];
  if (og < 0) return;
  float s0 = 0.f, s1 = 0.f, s2 = 0.f, s3 = 0.f;
#pragma unroll
  for (int sp = 0; sp < 8; ++sp) {
    const ushort4 v = *(const ushort4*)(Lp + ((size_t)sp * MPAD + row) * NCP + c4);
    s0 += bf2f(v.x); s1 += bf2f(v.y); s2 += bf2f(v.z); s3 += bf2f(v.w);
  }
  const int task = task_id[og];
  const float4 bb = *(const float4*)(b2 + (size_t)task * NC + c4);
  float4 o;
  o.x = s0 + bb.x; o.y = s1 + bb.y; o.z = s2 + bb.z; o.w = s3 + bb.w;
  *(float4*)(Out + (size_t)og * NC + c4) = o;
}

// ---------------------------------------------------------------------------
// Workspace layout (bytes) — total 56,688,640 (unchanged):
//   perm   int[9216]            @ 0           (36864)
//   starts int[9]               @ 37888
//   zrow   bf16[1024]           @ 40960       (2048)
//   XB     bf16[8192*1024]      @ 65536       (16777216)
//   W1T    bf16[8*1024*1024]    @ 18939904    (16777216)
//   W2F    bf16[8*8*32*512]     @ 35717120    (2097152)
//   Lp     bf16[8*9216*128]     @ 37814272    (18874368)  end 56688640
// ---------------------------------------------------------------------------
extern "C" void kernel_launch(void* const* d_in, const int* in_sizes, int n_in,
                              void* d_out, int out_size, void* d_ws, size_t ws_size,
                              hipStream_t stream) {
  const float* x       = (const float*)d_in[0];
  const int*   task_id = (const int*)d_in[1];
  const float* W1      = (const float*)d_in[2];
  const float* b1      = (const float*)d_in[3];
  const float* W2      = (const float*)d_in[4];
  const float* b2      = (const float*)d_in[5];
  float* out = (float*)d_out;

  char* ws = (char*)d_ws;
  int* perm   = (int*)(ws + 0);
  int* starts = (int*)(ws + 37888);
  unsigned short* zrow = (unsigned short*)(ws + 40960);
  unsigned short* XB  = (unsigned short*)(ws + 65536);
  unsigned short* W1T = (unsigned short*)(ws + 18939904);
  unsigned short* W2F = (unsigned short*)(ws + 35717120);
  unsigned short* Lp  = (unsigned short*)(ws + 37814272);

  sortpre_k<<<SORT_BLKS + W1_BLKS + W2_BLKS + XB_BLKS, 256, 0, stream>>>(
      task_id, x, W1, W1T, W2, W2F, XB, zrow, perm, starts);
  gemm_fused4<<<dim3(MPAD / 128, HID / 128), 256, 0, stream>>>(
      XB, W1T, W2F, b1, starts, perm, zrow, Lp);
  reduce_k<<<MPAD * 32 / 256, 256, 0, stream>>>(Lp, perm, task_id, b2, out);
}